// Round 1
// baseline (6112.920 us; speedup 1.0000x reference)
//
#include <hip/hip_runtime.h>

typedef unsigned short u16;
typedef unsigned int u32;
typedef unsigned long long u64;
typedef __attribute__((ext_vector_type(8))) short bf16x8;
typedef __attribute__((ext_vector_type(4))) float f32x4;
typedef __attribute__((ext_vector_type(16))) float f32x16;

__device__ __forceinline__ float b2f(u16 x) {
  union { u32 u; float f; } c; c.u = ((u32)x) << 16; return c.f;
}
__device__ __forceinline__ u16 f2b(float f) {
  union { float f; u32 u; } c; c.f = f;
  u32 u = c.u;
  return (u16)((u + 0x7FFFu + ((u >> 16) & 1u)) >> 16);
}
__device__ __forceinline__ float sigf(float x) { return 1.f / (1.f + __expf(-x)); }
__device__ __forceinline__ float tanhfast(float x) {
  float e = __expf(2.f * x);
  return 1.f - 2.f / (e + 1.f);
}
__device__ __forceinline__ float clampf(float x, float b) {
  return fminf(fmaxf(x, -b), b);
}
__device__ __forceinline__ float loadin(const void* p, long i, u32 isf32) {
  return isf32 ? ((const float*)p)[i] : b2f(((const u16*)p)[i]);
}
// L2-bypassing coherent read (straight from coherence point)
__device__ __forceinline__ u32 l3_load(const u32* p) {
  u32 v;
  asm volatile("global_load_dword %0, %1, off sc0 sc1\n\ts_waitcnt vmcnt(0)"
               : "=v"(v) : "v"(p) : "memory");
  return v;
}
// Write-through store (never lingers dirty in local L2)
__device__ __forceinline__ void l3_store(u32* p, u32 v) {
  asm volatile("global_store_dword %0, %1, off sc0 sc1" :: "v"(p), "v"(v) : "memory");
}
__device__ __forceinline__ void vm_drain() {
  asm volatile("s_waitcnt vmcnt(0)" ::: "memory");
}

// Layouts:
//  hsT[t][w8][b][j]  u16 idx = t*32768 + w8*512 + b*8 + j   (w8=64 col-octets)
//  xT [s][k8][b][j]  u16 idx = s*20480 + k8*512 + b*8 + j   (k8=40 col-octets)
// Each lane's 32x32x16 A-fragment (16B, k-octet granular) is contiguous in
// global memory -> A is loaded straight to registers, no LDS round-trip.

#define Z16 {0.f,0.f,0.f,0.f,0.f,0.f,0.f,0.f,0.f,0.f,0.f,0.f,0.f,0.f,0.f,0.f}

// poll 64 producer flags (one per lane of wave 0), then release the block
__device__ __forceinline__ void wait_flags(const u32* f, u32 tgt, int wv, int lane) {
  if (wv == 0) {
    const u32* fp = f + lane * 16;
    while (!__all((int)(l3_load(fp) >= tgt))) __builtin_amdgcn_s_sleep(1);
  }
  __syncthreads();
}

// N k16-steps: load N A-frags from global (single latency exposure), then MFMA
// against register-resident B-frags; two independent acc chains.
template <int N>
__device__ __forceinline__ void mfma_phase(const u16* __restrict__ ap,
                                           const bf16x8 (&bw)[16],
                                           f32x16& accA, f32x16& accB) {
  bf16x8 a[N];
#pragma unroll
  for (int i = 0; i < N; ++i) a[i] = *(const bf16x8*)(ap + i * 1024);
#pragma unroll
  for (int i = 0; i < N; ++i) {
    if (i & 1) accB = __builtin_amdgcn_mfma_f32_32x32x16_bf16(a[i], bw[i], accB, 0, 0, 0);
    else       accA = __builtin_amdgcn_mfma_f32_32x32x16_bf16(a[i], bw[i], accA, 0, 0, 0);
  }
}

// write the wave's 32x32 partial-z tile into its K-half ldsZ buffer.
// C layout (32x32x16): col=lane&31, row=(reg&3)+8*(reg>>2)+4*(lane>>5)
__device__ __forceinline__ void zwrite(float* __restrict__ zp,
                                       const f32x16& a, const f32x16& b,
                                       int mh, int l5, int l31) {
#pragma unroll
  for (int r = 0; r < 16; ++r) {
    int row = mh * 32 + (r & 3) + ((r >> 2) << 3) + (l5 << 2);
    zp[row * 33 + l31] = a[r] + b[r];
  }
}

__device__ __forceinline__ void gates_store(const float* __restrict__ ldsZ,
                                            const float* __restrict__ biasR,
                                            int w, int tid, int gb, int gj0, int t,
                                            u16* __restrict__ hs,
                                            float& c0, float& c1) {
  const float* zr0 = ldsZ + gb * 33;
  const float* zr1 = ldsZ + 64 * 33 + gb * 33;
  const float* br = biasR + w * 32;
  float hv[2];
#pragma unroll
  for (int q2 = 0; q2 < 2; ++q2) {
    int cb = (gj0 + q2) * 4;
    float zi = clampf(zr0[cb + 0] + zr1[cb + 0] + br[cb + 0], 30.f);
    float zf = clampf(zr0[cb + 1] + zr1[cb + 1] + br[cb + 1], 30.f);
    float zg = clampf(zr0[cb + 2] + zr1[cb + 2] + br[cb + 2], 30.f);
    float zo = clampf(zr0[cb + 3] + zr1[cb + 3] + br[cb + 3], 30.f);
    float co = q2 ? c1 : c0;
    float cn = clampf(sigf(zf) * co + sigf(zi) * tanhfast(zg), 64.f);
    if (q2) c1 = cn; else c0 = cn;
    hv[q2] = clampf(sigf(zo) * tanhfast(cn), 1.f);
  }
  u32 packed = (u32)f2b(hv[0]) | ((u32)f2b(hv[1]) << 16);
  l3_store((u32*)hs + (u64)t * 16384 + w * 256 + tid, packed);
  vm_drain();
}

// ---------------------------------------------------------------------------
__global__ __launch_bounds__(256) void detect_kernel(const u16* __restrict__ bih0,
                                                     u32* __restrict__ flag) {
  __shared__ u32 cnts[2];
  if (threadIdx.x < 2) cnts[threadIdx.x] = 0;
  __syncthreads();
  u32 huge = 0, zeros = 0;
  for (int i = threadIdx.x; i < 2048; i += 256) {
    u16 v = bih0[i];
    u32 e = (v >> 7) & 0xFFu;
    if (e >= 0xC0u) huge++;
    if (v == 0) zeros++;
  }
  atomicAdd(&cnts[0], huge);
  atomicAdd(&cnts[1], zeros);
  __syncthreads();
  if (threadIdx.x == 0) flag[0] = (cnts[0] >= 8u || cnts[1] >= 600u) ? 1u : 0u;
}

// ---------------------------------------------------------------------------
__global__ __launch_bounds__(256) void prep_kernel(
    const void* __restrict__ Wih0, const void* __restrict__ Whh0,
    const void* __restrict__ bih0, const void* __restrict__ bhh0,
    const void* __restrict__ Wih1, const void* __restrict__ Whh1,
    const void* __restrict__ bih1, const void* __restrict__ bhh1,
    const void* __restrict__ W1, const void* __restrict__ b1,
    const void* __restrict__ W2, const void* __restrict__ b2,
    const void* __restrict__ Wf, const void* __restrict__ bfv,
    u16* __restrict__ Wcat0, u16* __restrict__ Wcat1,
    float* __restrict__ biasR0, float* __restrict__ biasR1,
    u16* __restrict__ W1c, float* __restrict__ b1c,
    float* __restrict__ W2c, float* __restrict__ b2c,
    float* __restrict__ Wfc, float* __restrict__ bfc,
    const u32* __restrict__ flag)
{
  const u32 isf32 = flag[0];
  const int gid = blockIdx.x * 256 + threadIdx.x;
  const int gsz = gridDim.x * 256;
  for (int i = gid; i < 2048 * 832; i += gsz) {
    int np = i / 832, k = i - np * 832;
    int g = np & 3, j = np >> 2;
    long orig = g * 512 + j;
    u16 v;
    if (k < 320) v = (k < 300) ? f2b(loadin(Wih0, orig * 300 + k, isf32)) : (u16)0;
    else         v = f2b(loadin(Whh0, orig * 512 + (k - 320), isf32));
    Wcat0[i] = v;
  }
  for (int i = gid; i < 2048 * 1024; i += gsz) {
    int np = i >> 10, k = i & 1023;
    int g = np & 3, j = np >> 2;
    long orig = g * 512 + j;
    Wcat1[i] = (k < 512) ? f2b(loadin(Wih1, orig * 512 + k, isf32))
                         : f2b(loadin(Whh1, orig * 512 + (k - 512), isf32));
  }
  for (int i = gid; i < 2048; i += gsz) {
    int g = i & 3, j = i >> 2;
    long orig = g * 512 + j;
    biasR0[i] = loadin(bih0, orig, isf32) + loadin(bhh0, orig, isf32);
    biasR1[i] = loadin(bih1, orig, isf32) + loadin(bhh1, orig, isf32);
  }
  for (int i = gid; i < 256 * 1024; i += gsz) W1c[i] = f2b(loadin(W1, i, isf32));
  for (int i = gid; i < 256; i += gsz) {
    b1c[i] = loadin(b1, i, isf32);
    W2c[i] = loadin(W2, i, isf32);
  }
  for (int i = gid; i < 1024; i += gsz) Wfc[i] = f2b(loadin(Wf, i, isf32)), Wfc[i] = loadin(Wf, i, isf32);
  if (gid == 0) {
    b2c[0] = loadin(b2, 0, isf32);
    bfc[0] = loadin(bfv, 0, isf32);
  }
}

// ---------------------------------------------------------------------------
// gather -> xT layout: xT[s][c>>3][b][c&7]
// ---------------------------------------------------------------------------
__global__ __launch_bounds__(256) void gather_kernel(
    const int* __restrict__ xi, const void* __restrict__ embed,
    u16* __restrict__ xT, const u32* __restrict__ flag)
{
  const u32 isf32 = flag[0];
  const int r = blockIdx.x * 4 + (threadIdx.x >> 6);
  const int lane = threadIdx.x & 63;
  const int b = r & 63, s = r >> 6;
  const int idx = xi[b * 1024 + s];
  u16* dst = xT + (u64)s * 20480 + b * 8;
  if (!isf32) {
    const u16* src = (const u16*)embed + (u64)idx * 300;
    for (int c = lane; c < 300; c += 64) dst[(c >> 3) * 512 + (c & 7)] = src[c];
  } else {
    const float* src = (const float*)embed + (u64)idx * 300;
    for (int c = lane; c < 300; c += 64) dst[(c >> 3) * 512 + (c & 7)] = f2b(src[c]);
  }
  for (int c = 300 + lane; c < 320; c += 64) dst[(c >> 3) * 512 + (c & 7)] = 0;
}

// ---------------------------------------------------------------------------
// Fused persistent 2-layer LSTM. 128 WGs: 0-63 layer0, 64-127 layer1 (lag 1).
// Wave decomposition: wv -> (m-half = wv&1, k-half = wv>>1), 32x32x16 MFMA.
// B-weight fragments live in registers for the whole sequence; A-fragments
// load directly from global (layout-contiguous); c-state in registers.
// Layer0 computes its x-projection BEFORE polling (off the critical path);
// layer1 computes its own-recurrence phase before waiting on layer0's flags.
// ---------------------------------------------------------------------------
__global__ __launch_bounds__(256, 1) void lstm_fused(
    const u16* __restrict__ xT,
    const u16* __restrict__ Wcat0, const float* __restrict__ biasR0,
    const u16* __restrict__ Wcat1, const float* __restrict__ biasR1,
    u16* __restrict__ h0sT, u16* __restrict__ h1sT,
    u32* __restrict__ flags0, u32* __restrict__ flags1, int S)
{
  __shared__ __align__(16) float ldsZ[2 * 64 * 33];   // K-half partial z tiles
  __shared__ __align__(16) char ldsPad[81920];        // force 1 WG/CU
  if ((u64)xT == 0) ldsPad[threadIdx.x] = 1;          // never true; keeps pad

  const int layer = blockIdx.x >> 6;
  const int w = blockIdx.x & 63;
  const int tid = threadIdx.x;
  const int lane = tid & 63;
  const int wv = tid >> 6;
  const int mh = wv & 1;      // batch half (rows mh*32..mh*32+31)
  const int kh = wv >> 1;     // K half
  const int l5 = lane >> 5;   // k-octet select within k16 step
  const int l31 = lane & 31;

  const float* biasR = layer ? biasR1 : biasR0;
  u16* hs = layer ? h1sT : h0sT;
  u32* fown = layer ? flags1 : flags0;

  // ---- persistent B fragments (gate-row = w*32 + l31, k along 16B)
  bf16x8 bx[16], bh[16];
  if (layer == 0) {
    const u16* wr = Wcat0 + (u64)(w * 32 + l31) * 832 + l5 * 8;
#pragma unroll
    for (int i = 0; i < 10; ++i) bx[i] = *(const bf16x8*)(wr + (kh * 10 + i) * 16);
#pragma unroll
    for (int i = 0; i < 16; ++i) bh[i] = *(const bf16x8*)(wr + 320 + (kh * 16 + i) * 16);
  } else {
    const u16* wr = Wcat1 + (u64)(w * 32 + l31) * 1024 + l5 * 8;
#pragma unroll
    for (int i = 0; i < 16; ++i) bx[i] = *(const bf16x8*)(wr + (kh * 16 + i) * 16);
#pragma unroll
    for (int i = 0; i < 16; ++i) bh[i] = *(const bf16x8*)(wr + 512 + (kh * 16 + i) * 16);
  }

  const u64 abase = (u64)(mh * 32 + l31) * 8;   // A-frag row offset (u16)
  const int gb = tid >> 2;                      // gates: batch row
  const int gj0 = (tid & 3) * 2;                // gates: first h-col (of 8)
  float c0 = 0.f, c1 = 0.f;                     // c-state, register-resident
  float* zp = ldsZ + kh * (64 * 33);

  if (layer == 0) {
    for (int t = 0; t < S; ++t) {
      f32x16 accA = Z16, accB = Z16;
      // phase0: x projection — no recurrence dependency, runs pre-poll
      mfma_phase<10>(xT + (u64)t * 20480 + (u64)(kh * 20 + l5) * 512 + abase,
                     bx, accA, accB);
      if (t > 0) {
        wait_flags(flags0, (u32)t, wv, lane);
        mfma_phase<16>(h0sT + (u64)(t - 1) * 32768 + (u64)(kh * 32 + l5) * 512 + abase,
                       bh, accA, accB);
      }
      zwrite(zp, accA, accB, mh, l5, l31);
      __syncthreads();
      gates_store(ldsZ, biasR, w, tid, gb, gj0, t, hs, c0, c1);
      __syncthreads();
      if (tid == 0) l3_store(fown + w * 16, (u32)(t + 1));
    }
  } else {
    for (int t = 0; t < S; ++t) {
      f32x16 accA = Z16, accB = Z16;
      // own-recurrence phase first (own flags arrive early)
      if (t > 0) {
        wait_flags(flags1, (u32)t, wv, lane);
        mfma_phase<16>(h1sT + (u64)(t - 1) * 32768 + (u64)(kh * 32 + l5) * 512 + abase,
                       bh, accA, accB);
      }
      wait_flags(flags0, (u32)(t + 1), wv, lane);
      mfma_phase<16>(h0sT + (u64)t * 32768 + (u64)(kh * 32 + l5) * 512 + abase,
                     bx, accA, accB);
      zwrite(zp, accA, accB, mh, l5, l31);
      __syncthreads();
      gates_store(ldsZ, biasR, w, tid, gb, gj0, t, hs, c0, c1);
      __syncthreads();
      if (tid == 0) l3_store(fown + w * 16, (u32)(t + 1));
    }
  }
}

// ---------------------------------------------------------------------------
// gemm over hsT A: C[M=65536,N=256](bf16) = A_hsT @ B[N,K=512]^T. 128x128.
// ---------------------------------------------------------------------------
__global__ __launch_bounds__(256, 1) void gemm_hA(
    const u16* __restrict__ A,
    const u16* __restrict__ B, int ldb,
    u16* __restrict__ C, int ldc, int K)
{
  __shared__ __align__(16) u16 As[128 * 40];
  __shared__ __align__(16) u16 Bs[128 * 40];
  const int tid = threadIdx.x;
  const int bn = blockIdx.x * 128;
  const int bm = blockIdx.y * 128;
  const int lane = tid & 63;
  const int wv = tid >> 6;
  const int mh = wv >> 1, nh = wv & 1;
  const int lrow = lane & 15, kq = lane >> 4;
  const int sr = tid >> 1, sh = (tid & 1) * 16;
  const int m_ = bm + sr, s_ = m_ >> 6, bb = m_ & 63;
  f32x4 acc[4][4];
#pragma unroll
  for (int i = 0; i < 4; ++i)
#pragma unroll
    for (int j = 0; j < 4; ++j) acc[i][j] = {0.f, 0.f, 0.f, 0.f};

  for (int k0 = 0; k0 < K; k0 += 32) {
    const u16* ap = A + (u64)s_ * 32768 + (u64)((k0 + sh) >> 3) * 512 + bb * 8;
    *(bf16x8*)&As[sr * 40 + sh]     = *(const bf16x8*)ap;
    *(bf16x8*)&As[sr * 40 + sh + 8] = *(const bf16x8*)(ap + 512);
    *(bf16x8*)&Bs[sr * 40 + sh]     = *(const bf16x8*)(B + (u64)(bn + sr) * ldb + k0 + sh);
    *(bf16x8*)&Bs[sr * 40 + sh + 8] = *(const bf16x8*)(B + (u64)(bn + sr) * ldb + k0 + sh + 8);
    __syncthreads();
    bf16x8 af[4], bfr[4];
#pragma unroll
    for (int mt = 0; mt < 4; ++mt)
      af[mt] = *(const bf16x8*)&As[(mh * 64 + mt * 16 + lrow) * 40 + kq * 8];
#pragma unroll
    for (int nt = 0; nt < 4; ++nt)
      bfr[nt] = *(const bf16x8*)&Bs[(nh * 64 + nt * 16 + lrow) * 40 + kq * 8];
#pragma unroll
    for (int mt = 0; mt < 4; ++mt)
#pragma unroll
      for (int nt = 0; nt < 4; ++nt)
        acc[mt][nt] = __builtin_amdgcn_mfma_f32_16x16x32_bf16(af[mt], bfr[nt], acc[mt][nt], 0, 0, 0);
    __syncthreads();
  }
#pragma unroll
  for (int mt = 0; mt < 4; ++mt)
#pragma unroll
    for (int nt = 0; nt < 4; ++nt)
#pragma unroll
      for (int r = 0; r < 4; ++r) {
        int m = bm + mh * 64 + mt * 16 + kq * 4 + r;
        int n = bn + nh * 64 + nt * 16 + lrow;
        C[(u64)m * ldc + n] = f2b(clampf(acc[mt][nt][r], 60.f));
      }
}

// ---------------------------------------------------------------------------
__global__ __launch_bounds__(256) void part1_kernel(
    const u16* __restrict__ h1sT, const u16* __restrict__ W1c,
    const float* __restrict__ b1c, float* __restrict__ part1)
{
  __shared__ float hN[512];
  const int b = blockIdx.x;
  const int l = threadIdx.x;
  for (int i = l; i < 512; i += 256)
    hN[i] = b2f(h1sT[(u64)1023 * 32768 + (i >> 3) * 512 + b * 8 + (i & 7)]);
  __syncthreads();
  const u16* wrow = W1c + (u64)l * 1024;
  float acc = b1c[l];
  for (int k = 0; k < 512; ++k) acc += hN[k] * b2f(wrow[k]);
  part1[b * 256 + l] = clampf(acc, 60.f);
}

// ---------------------------------------------------------------------------
__global__ __launch_bounds__(256) void escore_kernel(
    const float* __restrict__ part1, const u16* __restrict__ part2,
    const float* __restrict__ W2c, const float* __restrict__ b2c,
    float* __restrict__ e)
{
  const int m = blockIdx.x * 4 + (threadIdx.x >> 6);
  const int lane = threadIdx.x & 63;
  const int b = m & 63, s = m >> 6;
  float acc = 0.f;
  for (int l = lane; l < 256; l += 64)
    acc += tanhfast(part1[b * 256 + l] + b2f(part2[(u64)m * 256 + l])) * W2c[l];
#pragma unroll
  for (int off = 32; off; off >>= 1) acc += __shfl_down(acc, off, 64);
  if (lane == 0) e[b * 1024 + s] = clampf(acc + b2c[0], 60.f);
}

// ---------------------------------------------------------------------------
__global__ __launch_bounds__(256) void finish_kernel(
    const float* __restrict__ e, const u16* __restrict__ h1sT,
    const float* __restrict__ Wfc, const float* __restrict__ bfc,
    void* __restrict__ dout, const u32* __restrict__ flag)
{
  __shared__ float sw[1024];
  __shared__ float red[4];
  __shared__ float hN[512];
  const u32 isf32 = flag[0];
  const int b = blockIdx.x;
  const int tid = threadIdx.x;
  const int lane = tid & 63, wv = tid >> 6;

  float mx = -1e30f;
  for (int s = tid; s < 1024; s += 256) {
    float v = e[b * 1024 + s];
    sw[s] = v;
    mx = fmaxf(mx, v);
  }
#pragma unroll
  for (int off = 1; off < 64; off <<= 1) mx = fmaxf(mx, __shfl_xor(mx, off, 64));
  if (lane == 0) red[wv] = mx;
  __syncthreads();
  mx = fmaxf(fmaxf(red[0], red[1]), fmaxf(red[2], red[3]));
  __syncthreads();

  float sum = 0.f;
  for (int s = tid; s < 1024; s += 256) {
    float p = __expf(sw[s] - mx);
    sw[s] = p;
    sum += p;
  }
#pragma unroll
  for (int off = 1; off < 64; off <<= 1) sum += __shfl_xor(sum, off, 64);
  if (lane == 0) red[wv] = sum;
  __syncthreads();
  sum = red[0] + red[1] + red[2] + red[3];
  float inv = 1.f / sum;
  for (int s = tid; s < 1024; s += 256) {
    float wn = sw[s] * inv;
    sw[s] = wn;
    if (isf32) ((float*)dout)[b * 1024 + s] = wn;
    else       ((u16*)dout)[b * 1024 + s] = f2b(wn);
  }
  for (int i = tid; i < 512; i += 256)
    hN[i] = b2f(h1sT[(u64)1023 * 32768 + (i >> 3) * 512 + b * 8 + (i & 7)]);
  __syncthreads();

  const int c0 = tid, c1 = tid + 256;
  const u64 off0 = (u64)(c0 >> 3) * 512 + b * 8 + (c0 & 7);
  const u64 off1 = (u64)(c1 >> 3) * 512 + b * 8 + (c1 & 7);
  float a0 = 0.f, a1 = 0.f;
  for (int s = 0; s < 1024; ++s) {
    const u16* hr = h1sT + (u64)s * 32768;
    float wn = sw[s];
    a0 += wn * b2f(hr[off0]);
    a1 += wn * b2f(hr[off1]);
  }
  float part = a0 * Wfc[c0] + a1 * Wfc[c1] + hN[c0] * Wfc[512 + c0] + hN[c1] * Wfc[512 + c1];
#pragma unroll
  for (int off = 1; off < 64; off <<= 1) part += __shfl_xor(part, off, 64);
  __syncthreads();
  if (lane == 0) red[wv] = part;
  __syncthreads();
  if (tid == 0) {
    float tot = clampf(red[0] + red[1] + red[2] + red[3] + bfc[0], 30.f);
    float o = sigf(tot);
    if (isf32) ((float*)dout)[65536 + b] = o;
    else       ((u16*)dout)[65536 + b] = f2b(o);
  }
}

// ---------------------------------------------------------------------------
extern "C" void kernel_launch(void* const* d_in, const int* in_sizes, int n_in,
                              void* d_out, int out_size, void* d_ws, size_t ws_size,
                              hipStream_t stream) {
  const int* x_index = (const int*)d_in[0];
  const void* embed = d_in[1];
  const void* Wih0 = d_in[2];
  const void* Whh0 = d_in[3];
  const void* bih0 = d_in[4];
  const void* bhh0 = d_in[5];
  const void* Wih1 = d_in[6];
  const void* Whh1 = d_in[7];
  const void* bih1 = d_in[8];
  const void* bhh1 = d_in[9];
  const void* W1 = d_in[10];
  const void* b1 = d_in[11];
  const void* W2 = d_in[12];
  const void* b2 = d_in[13];
  const void* Wf = d_in[14];
  const void* bfv = d_in[15];

  char* ws = (char*)d_ws;
  size_t off = 0;
  auto alloc = [&](size_t bytes) -> char* {
    char* p = ws + off;
    off += (bytes + 255) & ~(size_t)255;
    return p;
  };
  u32* flags0    = (u32*)alloc(64 * 16 * 4);   // one flag per 64B line
  u32* flags1    = (u32*)alloc(64 * 16 * 4);
  u32* flag      = (u32*)alloc(256);
  float* biasR0  = (float*)alloc(2048 * 4);
  float* biasR1  = (float*)alloc(2048 * 4);
  float* part1   = (float*)alloc(64 * 256 * 4);
  float* e       = (float*)alloc(64 * 1024 * 4);
  float* b1c     = (float*)alloc(256 * 4);
  float* W2c     = (float*)alloc(256 * 4);
  float* b2c     = (float*)alloc(16);
  float* Wfc     = (float*)alloc(1024 * 4);
  float* bfc     = (float*)alloc(16);
  u16* W1c       = (u16*)alloc((size_t)256 * 1024 * 2);
  u16* Wcat0     = (u16*)alloc((size_t)2048 * 832 * 2);
  u16* Wcat1     = (u16*)alloc((size_t)2048 * 1024 * 2);
  u16* xT        = (u16*)alloc((size_t)65536 * 320 * 2);
  u16* h0sT      = (u16*)alloc((size_t)65536 * 512 * 2);
  u16* h1sT      = (u16*)alloc((size_t)65536 * 512 * 2);
  u16* part2     = (u16*)alloc((size_t)65536 * 256 * 2);
  (void)ws_size; (void)in_sizes; (void)n_in; (void)out_size;

  hipMemsetAsync(flags0, 0, 64 * 16 * 4 * 2, stream);  // flags0 + flags1
  hipLaunchKernelGGL(detect_kernel, dim3(1), dim3(256), 0, stream,
                     (const u16*)bih0, flag);
  hipLaunchKernelGGL(prep_kernel, dim3(512), dim3(256), 0, stream,
                     Wih0, Whh0, bih0, bhh0, Wih1, Whh1, bih1, bhh1,
                     W1, b1, W2, b2, Wf, bfv,
                     Wcat0, Wcat1, biasR0, biasR1,
                     W1c, b1c, W2c, b2c, Wfc, bfc, flag);
  hipLaunchKernelGGL(gather_kernel, dim3(16384), dim3(256), 0, stream,
                     x_index, embed, xT, flag);
  hipLaunchKernelGGL(lstm_fused, dim3(128), dim3(256), 0, stream,
                     xT, Wcat0, biasR0, Wcat1, biasR1,
                     h0sT, h1sT, flags0, flags1, 1024);
  hipLaunchKernelGGL(part1_kernel, dim3(64), dim3(256), 0, stream,
                     h1sT, W1c, b1c, part1);
  hipLaunchKernelGGL(gemm_hA, dim3(2, 512), dim3(256), 0, stream,
                     h1sT, W1c + 512, 1024, part2, 256, 512);
  hipLaunchKernelGGL(escore_kernel, dim3(16384), dim3(256), 0, stream,
                     part1, part2, W2c, b2c, e);
  hipLaunchKernelGGL(finish_kernel, dim3(64), dim3(256), 0, stream,
                     e, h1sT, Wfc, bfc, d_out, flag);
}

// Round 2
// 5821.904 us; speedup vs baseline: 1.0500x; 1.0500x over previous
//
#include <hip/hip_runtime.h>

typedef unsigned short u16;
typedef unsigned int u32;
typedef unsigned long long u64;
typedef __attribute__((ext_vector_type(8))) short bf16x8;
typedef __attribute__((ext_vector_type(4))) float f32x4;
typedef __attribute__((ext_vector_type(16))) float f32x16;

__device__ __forceinline__ float b2f(u16 x) {
  union { u32 u; float f; } c; c.u = ((u32)x) << 16; return c.f;
}
__device__ __forceinline__ u16 f2b(float f) {
  union { float f; u32 u; } c; c.f = f;
  u32 u = c.u;
  return (u16)((u + 0x7FFFu + ((u >> 16) & 1u)) >> 16);
}
__device__ __forceinline__ float sigf(float x) { return 1.f / (1.f + __expf(-x)); }
__device__ __forceinline__ float tanhfast(float x) {
  float e = __expf(2.f * x);
  return 1.f - 2.f / (e + 1.f);
}
__device__ __forceinline__ float clampf(float x, float b) {
  return fminf(fmaxf(x, -b), b);
}
__device__ __forceinline__ float loadin(const void* p, long i, u32 isf32) {
  return isf32 ? ((const float*)p)[i] : b2f(((const u16*)p)[i]);
}
// L2-bypassing coherent read (straight from coherence point)
__device__ __forceinline__ u32 l3_load(const u32* p) {
  u32 v;
  asm volatile("global_load_dword %0, %1, off sc0 sc1\n\ts_waitcnt vmcnt(0)"
               : "=v"(v) : "v"(p) : "memory");
  return v;
}
// Write-through store (never lingers dirty in local L2)
__device__ __forceinline__ void l3_store(u32* p, u32 v) {
  asm volatile("global_store_dword %0, %1, off sc0 sc1" :: "v"(p), "v"(v) : "memory");
}
__device__ __forceinline__ void vm_drain() {
  asm volatile("s_waitcnt vmcnt(0)" ::: "memory");
}
// Opacify a register value: breaks the value<->memory link so the allocator
// cannot rematerialize the load; forces true VGPR residency across the loop.
__device__ __forceinline__ void pin(bf16x8& v) {
  asm volatile("" : "+v"(v));
}

// Layouts:
//  hsT[t][w8][b][j]  u16 idx = t*32768 + w8*512 + b*8 + j   (w8=64 col-octets)
//  xT [s][k8][b][j]  u16 idx = s*20480 + k8*512 + b*8 + j   (k8=40 col-octets)
// Each lane's 32x32x16 A-fragment (16B, k-octet granular) is contiguous in
// global memory -> A is loaded straight to registers, no LDS round-trip.

#define Z16 {0.f,0.f,0.f,0.f,0.f,0.f,0.f,0.f,0.f,0.f,0.f,0.f,0.f,0.f,0.f,0.f}

// poll 64 producer flags (one per lane of wave 0), then release the block
__device__ __forceinline__ void wait_flags(const u32* f, u32 tgt, int wv, int lane) {
  if (wv == 0) {
    const u32* fp = f + lane * 16;
    while (!__all((int)(l3_load(fp) >= tgt))) __builtin_amdgcn_s_sleep(1);
  }
  __syncthreads();
}

// N k16-steps: load N A-frags from global (single latency exposure), then MFMA
// against register-resident B-frags; two independent acc chains.
template <int N>
__device__ __forceinline__ void mfma_phase(const u16* __restrict__ ap,
                                           const bf16x8 (&bw)[16],
                                           f32x16& accA, f32x16& accB) {
  bf16x8 a[N];
#pragma unroll
  for (int i = 0; i < N; ++i) a[i] = *(const bf16x8*)(ap + i * 1024);
#pragma unroll
  for (int i = 0; i < N; ++i) {
    if (i & 1) accB = __builtin_amdgcn_mfma_f32_32x32x16_bf16(a[i], bw[i], accB, 0, 0, 0);
    else       accA = __builtin_amdgcn_mfma_f32_32x32x16_bf16(a[i], bw[i], accA, 0, 0, 0);
  }
}

// write the wave's 32x32 partial-z tile into its K-half ldsZ buffer.
// C layout (32x32x16): col=lane&31, row=(reg&3)+8*(reg>>2)+4*(lane>>5)
__device__ __forceinline__ void zwrite(float* __restrict__ zp,
                                       const f32x16& a, const f32x16& b,
                                       int mh, int l5, int l31) {
#pragma unroll
  for (int r = 0; r < 16; ++r) {
    int row = mh * 32 + (r & 3) + ((r >> 2) << 3) + (l5 << 2);
    zp[row * 33 + l31] = a[r] + b[r];
  }
}

__device__ __forceinline__ void gates_store(const float* __restrict__ ldsZ,
                                            const float* __restrict__ biasR,
                                            int w, int tid, int gb, int gj0, int t,
                                            u16* __restrict__ hs,
                                            float& c0, float& c1) {
  const float* zr0 = ldsZ + gb * 33;
  const float* zr1 = ldsZ + 64 * 33 + gb * 33;
  const float* br = biasR + w * 32;
  float hv[2];
#pragma unroll
  for (int q2 = 0; q2 < 2; ++q2) {
    int cb = (gj0 + q2) * 4;
    float zi = clampf(zr0[cb + 0] + zr1[cb + 0] + br[cb + 0], 30.f);
    float zf = clampf(zr0[cb + 1] + zr1[cb + 1] + br[cb + 1], 30.f);
    float zg = clampf(zr0[cb + 2] + zr1[cb + 2] + br[cb + 2], 30.f);
    float zo = clampf(zr0[cb + 3] + zr1[cb + 3] + br[cb + 3], 30.f);
    float co = q2 ? c1 : c0;
    float cn = clampf(sigf(zf) * co + sigf(zi) * tanhfast(zg), 64.f);
    if (q2) c1 = cn; else c0 = cn;
    hv[q2] = clampf(sigf(zo) * tanhfast(cn), 1.f);
  }
  u32 packed = (u32)f2b(hv[0]) | ((u32)f2b(hv[1]) << 16);
  l3_store((u32*)hs + (u64)t * 16384 + w * 256 + tid, packed);
  vm_drain();
}

// ---------------------------------------------------------------------------
__global__ __launch_bounds__(256) void detect_kernel(const u16* __restrict__ bih0,
                                                     u32* __restrict__ flag) {
  __shared__ u32 cnts[2];
  if (threadIdx.x < 2) cnts[threadIdx.x] = 0;
  __syncthreads();
  u32 huge = 0, zeros = 0;
  for (int i = threadIdx.x; i < 2048; i += 256) {
    u16 v = bih0[i];
    u32 e = (v >> 7) & 0xFFu;
    if (e >= 0xC0u) huge++;
    if (v == 0) zeros++;
  }
  atomicAdd(&cnts[0], huge);
  atomicAdd(&cnts[1], zeros);
  __syncthreads();
  if (threadIdx.x == 0) flag[0] = (cnts[0] >= 8u || cnts[1] >= 600u) ? 1u : 0u;
}

// ---------------------------------------------------------------------------
__global__ __launch_bounds__(256) void prep_kernel(
    const void* __restrict__ Wih0, const void* __restrict__ Whh0,
    const void* __restrict__ bih0, const void* __restrict__ bhh0,
    const void* __restrict__ Wih1, const void* __restrict__ Whh1,
    const void* __restrict__ bih1, const void* __restrict__ bhh1,
    const void* __restrict__ W1, const void* __restrict__ b1,
    const void* __restrict__ W2, const void* __restrict__ b2,
    const void* __restrict__ Wf, const void* __restrict__ bfv,
    u16* __restrict__ Wcat0, u16* __restrict__ Wcat1,
    float* __restrict__ biasR0, float* __restrict__ biasR1,
    u16* __restrict__ W1c, float* __restrict__ b1c,
    float* __restrict__ W2c, float* __restrict__ b2c,
    float* __restrict__ Wfc, float* __restrict__ bfc,
    const u32* __restrict__ flag)
{
  const u32 isf32 = flag[0];
  const int gid = blockIdx.x * 256 + threadIdx.x;
  const int gsz = gridDim.x * 256;
  for (int i = gid; i < 2048 * 832; i += gsz) {
    int np = i / 832, k = i - np * 832;
    int g = np & 3, j = np >> 2;
    long orig = g * 512 + j;
    u16 v;
    if (k < 320) v = (k < 300) ? f2b(loadin(Wih0, orig * 300 + k, isf32)) : (u16)0;
    else         v = f2b(loadin(Whh0, orig * 512 + (k - 320), isf32));
    Wcat0[i] = v;
  }
  for (int i = gid; i < 2048 * 1024; i += gsz) {
    int np = i >> 10, k = i & 1023;
    int g = np & 3, j = np >> 2;
    long orig = g * 512 + j;
    Wcat1[i] = (k < 512) ? f2b(loadin(Wih1, orig * 512 + k, isf32))
                         : f2b(loadin(Whh1, orig * 512 + (k - 512), isf32));
  }
  for (int i = gid; i < 2048; i += gsz) {
    int g = i & 3, j = i >> 2;
    long orig = g * 512 + j;
    biasR0[i] = loadin(bih0, orig, isf32) + loadin(bhh0, orig, isf32);
    biasR1[i] = loadin(bih1, orig, isf32) + loadin(bhh1, orig, isf32);
  }
  for (int i = gid; i < 256 * 1024; i += gsz) W1c[i] = f2b(loadin(W1, i, isf32));
  for (int i = gid; i < 256; i += gsz) {
    b1c[i] = loadin(b1, i, isf32);
    W2c[i] = loadin(W2, i, isf32);
  }
  for (int i = gid; i < 1024; i += gsz) Wfc[i] = loadin(Wf, i, isf32);
  if (gid == 0) {
    b2c[0] = loadin(b2, 0, isf32);
    bfc[0] = loadin(bfv, 0, isf32);
  }
}

// ---------------------------------------------------------------------------
// gather -> xT layout: xT[s][c>>3][b][c&7]
// ---------------------------------------------------------------------------
__global__ __launch_bounds__(256) void gather_kernel(
    const int* __restrict__ xi, const void* __restrict__ embed,
    u16* __restrict__ xT, const u32* __restrict__ flag)
{
  const u32 isf32 = flag[0];
  const int r = blockIdx.x * 4 + (threadIdx.x >> 6);
  const int lane = threadIdx.x & 63;
  const int b = r & 63, s = r >> 6;
  const int idx = xi[b * 1024 + s];
  u16* dst = xT + (u64)s * 20480 + b * 8;
  if (!isf32) {
    const u16* src = (const u16*)embed + (u64)idx * 300;
    for (int c = lane; c < 300; c += 64) dst[(c >> 3) * 512 + (c & 7)] = src[c];
  } else {
    const float* src = (const float*)embed + (u64)idx * 300;
    for (int c = lane; c < 300; c += 64) dst[(c >> 3) * 512 + (c & 7)] = f2b(src[c]);
  }
  for (int c = 300 + lane; c < 320; c += 64) dst[(c >> 3) * 512 + (c & 7)] = 0;
}

// ---------------------------------------------------------------------------
// Fused persistent 2-layer LSTM. 128 WGs: 0-63 layer0, 64-127 layer1 (lag 1).
// Wave decomposition: wv -> (m-half = wv&1, k-half = wv>>1), 32x32x16 MFMA.
// B-weight fragments PINNED in registers (opaque-asm) for the whole sequence;
// A-fragments load directly from global (layout-contiguous); c-state in regs.
// Layer0 computes its x-projection BEFORE polling (off the critical path);
// layer1 computes its own-recurrence phase before waiting on layer0's flags.
// ---------------------------------------------------------------------------
__global__ __launch_bounds__(256, 1) void lstm_fused(
    const u16* __restrict__ xT,
    const u16* __restrict__ Wcat0, const float* __restrict__ biasR0,
    const u16* __restrict__ Wcat1, const float* __restrict__ biasR1,
    u16* __restrict__ h0sT, u16* __restrict__ h1sT,
    u32* __restrict__ flags0, u32* __restrict__ flags1, int S)
{
  __shared__ __align__(16) float ldsZ[2 * 64 * 33];   // K-half partial z tiles

  const int layer = blockIdx.x >> 6;
  const int w = blockIdx.x & 63;
  const int tid = threadIdx.x;
  const int lane = tid & 63;
  const int wv = tid >> 6;
  const int mh = wv & 1;      // batch half (rows mh*32..mh*32+31)
  const int kh = wv >> 1;     // K half
  const int l5 = lane >> 5;   // k-octet select within k16 step
  const int l31 = lane & 31;

  const float* biasR = layer ? biasR1 : biasR0;
  u16* hs = layer ? h1sT : h0sT;
  u32* fown = layer ? flags1 : flags0;

  // ---- persistent B fragments (gate-row = w*32 + l31, k along 16B)
  bf16x8 bx[16], bh[16];
  if (layer == 0) {
    const u16* wr = Wcat0 + (u64)(w * 32 + l31) * 832 + l5 * 8;
#pragma unroll
    for (int i = 0; i < 10; ++i) bx[i] = *(const bf16x8*)(wr + (kh * 10 + i) * 16);
#pragma unroll
    for (int i = 0; i < 16; ++i) bh[i] = *(const bf16x8*)(wr + 320 + (kh * 16 + i) * 16);
#pragma unroll
    for (int i = 0; i < 10; ++i) pin(bx[i]);
#pragma unroll
    for (int i = 0; i < 16; ++i) pin(bh[i]);
  } else {
    const u16* wr = Wcat1 + (u64)(w * 32 + l31) * 1024 + l5 * 8;
#pragma unroll
    for (int i = 0; i < 16; ++i) bx[i] = *(const bf16x8*)(wr + (kh * 16 + i) * 16);
#pragma unroll
    for (int i = 0; i < 16; ++i) bh[i] = *(const bf16x8*)(wr + 512 + (kh * 16 + i) * 16);
#pragma unroll
    for (int i = 0; i < 16; ++i) pin(bx[i]);
#pragma unroll
    for (int i = 0; i < 16; ++i) pin(bh[i]);
  }

  const u64 abase = (u64)(mh * 32 + l31) * 8;   // A-frag row offset (u16)
  const int gb = tid >> 2;                      // gates: batch row
  const int gj0 = (tid & 3) * 2;                // gates: first h-col (of 8)
  float c0 = 0.f, c1 = 0.f;                     // c-state, register-resident
  float* zp = ldsZ + kh * (64 * 33);

  if (layer == 0) {
    for (int t = 0; t < S; ++t) {
      f32x16 accA = Z16, accB = Z16;
      // phase0: x projection — no recurrence dependency, runs pre-poll
      mfma_phase<10>(xT + (u64)t * 20480 + (u64)(kh * 20 + l5) * 512 + abase,
                     bx, accA, accB);
      if (t > 0) {
        wait_flags(flags0, (u32)t, wv, lane);
        mfma_phase<16>(h0sT + (u64)(t - 1) * 32768 + (u64)(kh * 32 + l5) * 512 + abase,
                       bh, accA, accB);
      }
      zwrite(zp, accA, accB, mh, l5, l31);
      __syncthreads();
      gates_store(ldsZ, biasR, w, tid, gb, gj0, t, hs, c0, c1);
      __syncthreads();
      if (tid == 0) l3_store(fown + w * 16, (u32)(t + 1));
    }
  } else {
    for (int t = 0; t < S; ++t) {
      f32x16 accA = Z16, accB = Z16;
      // own-recurrence phase first (own flags arrive early)
      if (t > 0) {
        wait_flags(flags1, (u32)t, wv, lane);
        mfma_phase<16>(h1sT + (u64)(t - 1) * 32768 + (u64)(kh * 32 + l5) * 512 + abase,
                       bh, accA, accB);
      }
      wait_flags(flags0, (u32)(t + 1), wv, lane);
      mfma_phase<16>(h0sT + (u64)t * 32768 + (u64)(kh * 32 + l5) * 512 + abase,
                     bx, accA, accB);
      zwrite(zp, accA, accB, mh, l5, l31);
      __syncthreads();
      gates_store(ldsZ, biasR, w, tid, gb, gj0, t, hs, c0, c1);
      __syncthreads();
      if (tid == 0) l3_store(fown + w * 16, (u32)(t + 1));
    }
  }
}

// ---------------------------------------------------------------------------
// gemm over hsT A: C[M=65536,N=256](bf16) = A_hsT @ B[N,K=512]^T. 128x128.
// ---------------------------------------------------------------------------
__global__ __launch_bounds__(256, 1) void gemm_hA(
    const u16* __restrict__ A,
    const u16* __restrict__ B, int ldb,
    u16* __restrict__ C, int ldc, int K)
{
  __shared__ __align__(16) u16 As[128 * 40];
  __shared__ __align__(16) u16 Bs[128 * 40];
  const int tid = threadIdx.x;
  const int bn = blockIdx.x * 128;
  const int bm = blockIdx.y * 128;
  const int lane = tid & 63;
  const int wv = tid >> 6;
  const int mh = wv >> 1, nh = wv & 1;
  const int lrow = lane & 15, kq = lane >> 4;
  const int sr = tid >> 1, sh = (tid & 1) * 16;
  const int m_ = bm + sr, s_ = m_ >> 6, bb = m_ & 63;
  f32x4 acc[4][4];
#pragma unroll
  for (int i = 0; i < 4; ++i)
#pragma unroll
    for (int j = 0; j < 4; ++j) acc[i][j] = {0.f, 0.f, 0.f, 0.f};

  for (int k0 = 0; k0 < K; k0 += 32) {
    const u16* ap = A + (u64)s_ * 32768 + (u64)((k0 + sh) >> 3) * 512 + bb * 8;
    *(bf16x8*)&As[sr * 40 + sh]     = *(const bf16x8*)ap;
    *(bf16x8*)&As[sr * 40 + sh + 8] = *(const bf16x8*)(ap + 512);
    *(bf16x8*)&Bs[sr * 40 + sh]     = *(const bf16x8*)(B + (u64)(bn + sr) * ldb + k0 + sh);
    *(bf16x8*)&Bs[sr * 40 + sh + 8] = *(const bf16x8*)(B + (u64)(bn + sr) * ldb + k0 + sh + 8);
    __syncthreads();
    bf16x8 af[4], bfr[4];
#pragma unroll
    for (int mt = 0; mt < 4; ++mt)
      af[mt] = *(const bf16x8*)&As[(mh * 64 + mt * 16 + lrow) * 40 + kq * 8];
#pragma unroll
    for (int nt = 0; nt < 4; ++nt)
      bfr[nt] = *(const bf16x8*)&Bs[(nh * 64 + nt * 16 + lrow) * 40 + kq * 8];
#pragma unroll
    for (int mt = 0; mt < 4; ++mt)
#pragma unroll
      for (int nt = 0; nt < 4; ++nt)
        acc[mt][nt] = __builtin_amdgcn_mfma_f32_16x16x32_bf16(af[mt], bfr[nt], acc[mt][nt], 0, 0, 0);
    __syncthreads();
  }
#pragma unroll
  for (int mt = 0; mt < 4; ++mt)
#pragma unroll
    for (int nt = 0; nt < 4; ++nt)
#pragma unroll
      for (int r = 0; r < 4; ++r) {
        int m = bm + mh * 64 + mt * 16 + kq * 4 + r;
        int n = bn + nh * 64 + nt * 16 + lrow;
        C[(u64)m * ldc + n] = f2b(clampf(acc[mt][nt][r], 60.f));
      }
}

// ---------------------------------------------------------------------------
__global__ __launch_bounds__(256) void part1_kernel(
    const u16* __restrict__ h1sT, const u16* __restrict__ W1c,
    const float* __restrict__ b1c, float* __restrict__ part1)
{
  __shared__ float hN[512];
  const int b = blockIdx.x;
  const int l = threadIdx.x;
  for (int i = l; i < 512; i += 256)
    hN[i] = b2f(h1sT[(u64)1023 * 32768 + (i >> 3) * 512 + b * 8 + (i & 7)]);
  __syncthreads();
  const u16* wrow = W1c + (u64)l * 1024;
  float acc = b1c[l];
  for (int k = 0; k < 512; ++k) acc += hN[k] * b2f(wrow[k]);
  part1[b * 256 + l] = clampf(acc, 60.f);
}

// ---------------------------------------------------------------------------
__global__ __launch_bounds__(256) void escore_kernel(
    const float* __restrict__ part1, const u16* __restrict__ part2,
    const float* __restrict__ W2c, const float* __restrict__ b2c,
    float* __restrict__ e)
{
  const int m = blockIdx.x * 4 + (threadIdx.x >> 6);
  const int lane = threadIdx.x & 63;
  const int b = m & 63, s = m >> 6;
  float acc = 0.f;
  for (int l = lane; l < 256; l += 64)
    acc += tanhfast(part1[b * 256 + l] + b2f(part2[(u64)m * 256 + l])) * W2c[l];
#pragma unroll
  for (int off = 32; off; off >>= 1) acc += __shfl_down(acc, off, 64);
  if (lane == 0) e[b * 1024 + s] = clampf(acc + b2c[0], 60.f);
}

// ---------------------------------------------------------------------------
__global__ __launch_bounds__(256) void finish_kernel(
    const float* __restrict__ e, const u16* __restrict__ h1sT,
    const float* __restrict__ Wfc, const float* __restrict__ bfc,
    void* __restrict__ dout, const u32* __restrict__ flag)
{
  __shared__ float sw[1024];
  __shared__ float red[4];
  __shared__ float hN[512];
  const u32 isf32 = flag[0];
  const int b = blockIdx.x;
  const int tid = threadIdx.x;
  const int lane = tid & 63, wv = tid >> 6;

  float mx = -1e30f;
  for (int s = tid; s < 1024; s += 256) {
    float v = e[b * 1024 + s];
    sw[s] = v;
    mx = fmaxf(mx, v);
  }
#pragma unroll
  for (int off = 1; off < 64; off <<= 1) mx = fmaxf(mx, __shfl_xor(mx, off, 64));
  if (lane == 0) red[wv] = mx;
  __syncthreads();
  mx = fmaxf(fmaxf(red[0], red[1]), fmaxf(red[2], red[3]));
  __syncthreads();

  float sum = 0.f;
  for (int s = tid; s < 1024; s += 256) {
    float p = __expf(sw[s] - mx);
    sw[s] = p;
    sum += p;
  }
#pragma unroll
  for (int off = 1; off < 64; off <<= 1) sum += __shfl_xor(sum, off, 64);
  if (lane == 0) red[wv] = sum;
  __syncthreads();
  sum = red[0] + red[1] + red[2] + red[3];
  float inv = 1.f / sum;
  for (int s = tid; s < 1024; s += 256) {
    float wn = sw[s] * inv;
    sw[s] = wn;
    if (isf32) ((float*)dout)[b * 1024 + s] = wn;
    else       ((u16*)dout)[b * 1024 + s] = f2b(wn);
  }
  for (int i = tid; i < 512; i += 256)
    hN[i] = b2f(h1sT[(u64)1023 * 32768 + (i >> 3) * 512 + b * 8 + (i & 7)]);
  __syncthreads();

  const int c0 = tid, c1 = tid + 256;
  const u64 off0 = (u64)(c0 >> 3) * 512 + b * 8 + (c0 & 7);
  const u64 off1 = (u64)(c1 >> 3) * 512 + b * 8 + (c1 & 7);
  float a0 = 0.f, a1 = 0.f;
  for (int s = 0; s < 1024; ++s) {
    const u16* hr = h1sT + (u64)s * 32768;
    float wn = sw[s];
    a0 += wn * b2f(hr[off0]);
    a1 += wn * b2f(hr[off1]);
  }
  float part = a0 * Wfc[c0] + a1 * Wfc[c1] + hN[c0] * Wfc[512 + c0] + hN[c1] * Wfc[512 + c1];
#pragma unroll
  for (int off = 1; off < 64; off <<= 1) part += __shfl_xor(part, off, 64);
  __syncthreads();
  if (lane == 0) red[wv] = part;
  __syncthreads();
  if (tid == 0) {
    float tot = clampf(red[0] + red[1] + red[2] + red[3] + bfc[0], 30.f);
    float o = sigf(tot);
    if (isf32) ((float*)dout)[65536 + b] = o;
    else       ((u16*)dout)[65536 + b] = f2b(o);
  }
}

// ---------------------------------------------------------------------------
extern "C" void kernel_launch(void* const* d_in, const int* in_sizes, int n_in,
                              void* d_out, int out_size, void* d_ws, size_t ws_size,
                              hipStream_t stream) {
  const int* x_index = (const int*)d_in[0];
  const void* embed = d_in[1];
  const void* Wih0 = d_in[2];
  const void* Whh0 = d_in[3];
  const void* bih0 = d_in[4];
  const void* bhh0 = d_in[5];
  const void* Wih1 = d_in[6];
  const void* Whh1 = d_in[7];
  const void* bih1 = d_in[8];
  const void* bhh1 = d_in[9];
  const void* W1 = d_in[10];
  const void* b1 = d_in[11];
  const void* W2 = d_in[12];
  const void* b2 = d_in[13];
  const void* Wf = d_in[14];
  const void* bfv = d_in[15];

  char* ws = (char*)d_ws;
  size_t off = 0;
  auto alloc = [&](size_t bytes) -> char* {
    char* p = ws + off;
    off += (bytes + 255) & ~(size_t)255;
    return p;
  };
  u32* flags0    = (u32*)alloc(64 * 16 * 4);   // one flag per 64B line
  u32* flags1    = (u32*)alloc(64 * 16 * 4);
  u32* flag      = (u32*)alloc(256);
  float* biasR0  = (float*)alloc(2048 * 4);
  float* biasR1  = (float*)alloc(2048 * 4);
  float* part1   = (float*)alloc(64 * 256 * 4);
  float* e       = (float*)alloc(64 * 1024 * 4);
  float* b1c     = (float*)alloc(256 * 4);
  float* W2c     = (float*)alloc(256 * 4);
  float* b2c     = (float*)alloc(16);
  float* Wfc     = (float*)alloc(1024 * 4);
  float* bfc     = (float*)alloc(16);
  u16* W1c       = (u16*)alloc((size_t)256 * 1024 * 2);
  u16* Wcat0     = (u16*)alloc((size_t)2048 * 832 * 2);
  u16* Wcat1     = (u16*)alloc((size_t)2048 * 1024 * 2);
  u16* xT        = (u16*)alloc((size_t)65536 * 320 * 2);
  u16* h0sT      = (u16*)alloc((size_t)65536 * 512 * 2);
  u16* h1sT      = (u16*)alloc((size_t)65536 * 512 * 2);
  u16* part2     = (u16*)alloc((size_t)65536 * 256 * 2);
  (void)ws_size; (void)in_sizes; (void)n_in; (void)out_size;

  hipMemsetAsync(flags0, 0, 64 * 16 * 4 * 2, stream);  // flags0 + flags1
  hipLaunchKernelGGL(detect_kernel, dim3(1), dim3(256), 0, stream,
                     (const u16*)bih0, flag);
  hipLaunchKernelGGL(prep_kernel, dim3(512), dim3(256), 0, stream,
                     Wih0, Whh0, bih0, bhh0, Wih1, Whh1, bih1, bhh1,
                     W1, b1, W2, b2, Wf, bfv,
                     Wcat0, Wcat1, biasR0, biasR1,
                     W1c, b1c, W2c, b2c, Wfc, bfc, flag);
  hipLaunchKernelGGL(gather_kernel, dim3(16384), dim3(256), 0, stream,
                     x_index, embed, xT, flag);
  hipLaunchKernelGGL(lstm_fused, dim3(128), dim3(256), 0, stream,
                     xT, Wcat0, biasR0, Wcat1, biasR1,
                     h0sT, h1sT, flags0, flags1, 1024);
  hipLaunchKernelGGL(part1_kernel, dim3(64), dim3(256), 0, stream,
                     h1sT, W1c, b1c, part1);
  hipLaunchKernelGGL(gemm_hA, dim3(2, 512), dim3(256), 0, stream,
                     h1sT, W1c + 512, 1024, part2, 256, 512);
  hipLaunchKernelGGL(escore_kernel, dim3(16384), dim3(256), 0, stream,
                     part1, part2, W2c, b2c, e);
  hipLaunchKernelGGL(finish_kernel, dim3(64), dim3(256), 0, stream,
                     e, h1sT, Wfc, bfc, d_out, flag);
}